// Round 1
// baseline (3245.898 us; speedup 1.0000x reference)
//
#include <hip/hip_runtime.h>
#include <math.h>

#define N_NODES   100000
#define N_EDGES   1600000
#define NODE_F    128
#define EDGE_F    128
#define GLOB_F    64
#define N_GRAPHS  256
#define HIDDEN    128
#define IN_DIM    320   // 128 + 128 + 64

// ---------------------------------------------------------------------------
// Kernel 1: scatter-add edge features + counts onto destination nodes.
// 8 edges per 256-thread block; 32 lanes per edge, float4 per lane.
// ---------------------------------------------------------------------------
__global__ __launch_bounds__(256) void scatter_add_kernel(
    const float* __restrict__ edge_feats,
    const int* __restrict__ dst,          // edge_index row 1
    float* __restrict__ sums,             // [N_NODES, 128]
    float* __restrict__ cnts)             // [N_NODES]
{
    int e = blockIdx.x * 8 + (threadIdx.x >> 5);
    int lane = threadIdx.x & 31;
    if (e >= N_EDGES) return;
    int d = dst[e];
    const float4 v = *reinterpret_cast<const float4*>(
        edge_feats + (size_t)e * EDGE_F + lane * 4);
    float* s = sums + (size_t)d * EDGE_F + lane * 4;
    atomicAdd(s + 0, v.x);
    atomicAdd(s + 1, v.y);
    atomicAdd(s + 2, v.z);
    atomicAdd(s + 3, v.w);
    if (lane == 0) atomicAdd(cnts + d, 1.0f);
}

// ---------------------------------------------------------------------------
// Kernel 2: fused concat + GEMM (X[100K,320] @ W^T[320,128]) + shifted softplus.
// Block: 256 threads, 16 rows. o = tid&127 (output col), rg = tid>>7.
// Each thread accumulates 8 rows (rg, rg+2, ..., rg+14) for its column o.
// X rows staged in LDS (broadcast reads); W staged in k-tiles of 32,
// transposed with +1 padding (conflict-free write & read).
// ---------------------------------------------------------------------------
__global__ __launch_bounds__(256) void fused_gemm_kernel(
    const float* __restrict__ node_feats,   // [N_NODES, 128]
    const float* __restrict__ sums,         // [N_NODES, 128]
    const float* __restrict__ cnts,         // [N_NODES]
    const float* __restrict__ glob,         // [N_GRAPHS, 64]
    const int* __restrict__ batch,          // [N_NODES]
    const float* __restrict__ W,            // [HIDDEN, IN_DIM] row-major
    float* __restrict__ out)                // [N_NODES, HIDDEN]
{
    __shared__ float xs[16][IN_DIM];       // 20480 B
    __shared__ float wt[32][HIDDEN + 1];   // 16512 B, padded
    __shared__ float invc[16];
    __shared__ int   bidx[16];

    const int tid = threadIdx.x;
    const int o   = tid & 127;
    const int rg  = tid >> 7;
    const int row0 = blockIdx.x * 16;

    if (tid < 16) {
        int gr = row0 + tid;
        float c = cnts[gr];
        invc[tid] = 1.0f / fmaxf(c, 1.0f);
        bidx[tid] = batch[gr];
    }
    __syncthreads();

    // Build the 16 concat rows in LDS.
    for (int i = tid; i < 16 * IN_DIM; i += 256) {
        int r = i / IN_DIM;
        int k = i - r * IN_DIM;
        int gr = row0 + r;
        float v;
        if (k < NODE_F) {
            v = node_feats[(size_t)gr * NODE_F + k];
        } else if (k < NODE_F + EDGE_F) {
            v = sums[(size_t)gr * EDGE_F + (k - NODE_F)] * invc[r];
        } else {
            v = glob[bidx[r] * GLOB_F + (k - NODE_F - EDGE_F)];
        }
        xs[r][k] = v;
    }
    __syncthreads();

    float acc[8] = {0.f, 0.f, 0.f, 0.f, 0.f, 0.f, 0.f, 0.f};

    for (int k0 = 0; k0 < IN_DIM; k0 += 32) {
        // Stage W k-tile transposed: wt[kk][o] = W[o][k0+kk].
        {
            int kk = tid & 31;
            int ob = tid >> 5;     // 0..7
            #pragma unroll
            for (int oo = 0; oo < 16; ++oo) {
                int oc = ob + oo * 8;
                wt[kk][oc] = W[(size_t)oc * IN_DIM + k0 + kk];
            }
        }
        __syncthreads();

        #pragma unroll
        for (int kk = 0; kk < 32; kk += 4) {
            const float w0 = wt[kk + 0][o];
            const float w1 = wt[kk + 1][o];
            const float w2 = wt[kk + 2][o];
            const float w3 = wt[kk + 3][o];
            #pragma unroll
            for (int rr = 0; rr < 8; ++rr) {
                const float4 x = *reinterpret_cast<const float4*>(
                    &xs[rg + rr * 2][k0 + kk]);
                acc[rr] = fmaf(x.x, w0, acc[rr]);
                acc[rr] = fmaf(x.y, w1, acc[rr]);
                acc[rr] = fmaf(x.z, w2, acc[rr]);
                acc[rr] = fmaf(x.w, w3, acc[rr]);
            }
        }
        __syncthreads();
    }

    // Shifted softplus epilogue: softplus(h) - ln(2), numerically stable.
    const float LN2 = 0.69314718055994530942f;
    #pragma unroll
    for (int rr = 0; rr < 8; ++rr) {
        int r = rg + rr * 2;
        float h = acc[rr];
        float sp = fmaxf(h, 0.0f) + log1pf(expf(-fabsf(h)));
        out[(size_t)(row0 + r) * HIDDEN + o] = sp - LN2;
    }
}

// ---------------------------------------------------------------------------
extern "C" void kernel_launch(void* const* d_in, const int* in_sizes, int n_in,
                              void* d_out, int out_size, void* d_ws, size_t ws_size,
                              hipStream_t stream) {
    const float* node_feats = (const float*)d_in[0];   // [100000,128]
    const float* edge_feats = (const float*)d_in[1];   // [1600000,128]
    const float* glob       = (const float*)d_in[2];   // [256,64]
    const float* W          = (const float*)d_in[3];   // [128,320]
    const int*   edge_index = (const int*)d_in[4];     // [2,1600000]
    const int*   batch      = (const int*)d_in[5];     // [100000]
    float* out = (float*)d_out;                        // [100000,128]

    float* sums = (float*)d_ws;                        // [100000*128]
    float* cnts = sums + (size_t)N_NODES * EDGE_F;     // [100000]

    size_t zero_bytes = ((size_t)N_NODES * EDGE_F + N_NODES) * sizeof(float);
    hipMemsetAsync(d_ws, 0, zero_bytes, stream);

    const int* dst = edge_index + N_EDGES;  // row 1 = destinations

    dim3 sblk(256);
    dim3 sgrd(N_EDGES / 8);                 // 200000 blocks, exact
    scatter_add_kernel<<<sgrd, sblk, 0, stream>>>(edge_feats, dst, sums, cnts);

    dim3 gblk(256);
    dim3 ggrd(N_NODES / 16);                // 6250 blocks, exact
    fused_gemm_kernel<<<ggrd, gblk, 0, stream>>>(
        node_feats, sums, cnts, glob, batch, W, out);
}

// Round 2
// 568.714 us; speedup vs baseline: 5.7074x; 5.7074x over previous
//
#include <hip/hip_runtime.h>
#include <math.h>

#define N_NODES   100000
#define N_EDGES   1600000
#define NODE_F    128
#define EDGE_F    128
#define GLOB_F    64
#define N_GRAPHS  256
#define HIDDEN    128
#define IN_DIM    320   // 128 + 128 + 64

#define SCAN_CHUNK 2048
#define NSCAN ((N_NODES + SCAN_CHUNK - 1) / SCAN_CHUNK)   // 49

typedef __bf16 bf16x8 __attribute__((ext_vector_type(8)));
typedef __bf16 bf16x4 __attribute__((ext_vector_type(4)));
typedef float  f32x4  __attribute__((ext_vector_type(4)));

__device__ __forceinline__ void cvt_store4(__bf16* p, float x, float y, float z, float w) {
    bf16x4 b = { (__bf16)x, (__bf16)y, (__bf16)z, (__bf16)w };
    *reinterpret_cast<bf16x4*>(p) = b;
}

// ---------------------------------------------------------------------------
// W (f32 [128,320]) -> bf16, once.
// ---------------------------------------------------------------------------
__global__ __launch_bounds__(256) void wbf_kernel(const float* __restrict__ W,
                                                  __bf16* __restrict__ wbf) {
    int i = blockIdx.x * 256 + threadIdx.x;   // 160 blocks x 256 = 40960 exact
    wbf[i] = (__bf16)W[i];
}

// ---------------------------------------------------------------------------
// CSR build: histogram -> scan -> fill
// ---------------------------------------------------------------------------
__global__ __launch_bounds__(256) void hist_kernel(const int* __restrict__ dst,
                                                   int* __restrict__ counts) {
    int i = blockIdx.x * 256 + threadIdx.x;   // 6250 x 256 = 1.6M exact
    if (i < N_EDGES) atomicAdd(&counts[dst[i]], 1);
}

__global__ __launch_bounds__(256) void scan1_kernel(const int* __restrict__ counts,
                                                    int* __restrict__ partial) {
    __shared__ int red[256];
    int tid = threadIdx.x;
    int base = blockIdx.x * SCAN_CHUNK + tid * 8;
    int s = 0;
    #pragma unroll
    for (int j = 0; j < 8; ++j) {
        int idx = base + j;
        if (idx < N_NODES) s += counts[idx];
    }
    red[tid] = s;
    __syncthreads();
    for (int off = 128; off > 0; off >>= 1) {
        if (tid < off) red[tid] += red[tid + off];
        __syncthreads();
    }
    if (tid == 0) partial[blockIdx.x] = red[0];
}

__global__ __launch_bounds__(64) void scan2_kernel(const int* __restrict__ partial,
                                                   int* __restrict__ pscan) {
    if (threadIdx.x == 0) {
        int run = 0;
        for (int b = 0; b < NSCAN; ++b) { pscan[b] = run; run += partial[b]; }
    }
}

__global__ __launch_bounds__(256) void scan3_kernel(const int* __restrict__ counts,
                                                    const int* __restrict__ pscan,
                                                    int* __restrict__ offs,
                                                    int* __restrict__ cursor) {
    __shared__ int ts[256];
    int tid = threadIdx.x;
    int base = blockIdx.x * SCAN_CHUNK + tid * 8;
    int c[8];
    int tot = 0;
    #pragma unroll
    for (int j = 0; j < 8; ++j) {
        int idx = base + j;
        c[j] = (idx < N_NODES) ? counts[idx] : 0;
        tot += c[j];
    }
    ts[tid] = tot;
    __syncthreads();
    for (int off = 1; off < 256; off <<= 1) {
        int v = 0;
        if (tid >= off) v = ts[tid - off];
        __syncthreads();
        if (tid >= off) ts[tid] += v;
        __syncthreads();
    }
    int run = pscan[blockIdx.x] + ts[tid] - tot;   // exclusive prefix
    #pragma unroll
    for (int j = 0; j < 8; ++j) {
        int idx = base + j;
        if (idx < N_NODES) { offs[idx] = run; cursor[idx] = run; run += c[j]; }
    }
    if (blockIdx.x == 0 && tid == 0) offs[N_NODES] = N_EDGES;
}

__global__ __launch_bounds__(256) void fill_kernel(const int* __restrict__ dst,
                                                   int* __restrict__ cursor,
                                                   int* __restrict__ eid) {
    int i = blockIdx.x * 256 + threadIdx.x;
    if (i < N_EDGES) {
        int d = dst[i];
        int pos = atomicAdd(&cursor[d], 1);
        eid[pos] = i;
    }
}

// ---------------------------------------------------------------------------
// Fused: CSR gather-mean + concat (into LDS as bf16) + MFMA GEMM + softplus.
// Block = 256 threads (4 waves), 32 rows x 128 cols of output.
// Per wave: cols [wv*32, wv*32+32), 2 row-tiles x 2 col-tiles of 16x16 MFMA.
// ---------------------------------------------------------------------------
#define ROWS 32
#define XSTR (IN_DIM + 8)     // 328 bf16 -> 656 B row stride (16-aligned)
#define WSTR 40               // 32 + 8 pad -> 80 B row stride (16-aligned)

__global__ __launch_bounds__(256) void fused_kernel(
    const float* __restrict__ node_feats,   // [N_NODES,128]
    const float* __restrict__ edge_feats,   // [N_EDGES,128]
    const float* __restrict__ glob,         // [256,64]
    const int*   __restrict__ batch,        // [N_NODES]
    const __bf16* __restrict__ wbf,         // [128,320] bf16
    const int*   __restrict__ offs,         // [N_NODES+1]
    const int*   __restrict__ eid,          // [N_EDGES]
    float* __restrict__ out)                // [N_NODES,128]
{
    __shared__ __bf16 xs[ROWS * XSTR];      // 20992 B
    __shared__ __bf16 wb[HIDDEN * WSTR];    // 10240 B

    const int tid  = threadIdx.x;
    const int row0 = blockIdx.x * ROWS;
    const int wv   = tid >> 6;
    const int lane = tid & 63;

    // ---- stage node features -> xs[:, 0:128)
    #pragma unroll
    for (int it = 0; it < 4; ++it) {
        int i = tid + it * 256;             // 0..1023
        int r = i >> 5, k4 = i & 31;
        float4 v = *reinterpret_cast<const float4*>(
            node_feats + (size_t)(row0 + r) * NODE_F + k4 * 4);
        cvt_store4(&xs[r * XSTR + k4 * 4], v.x, v.y, v.z, v.w);
    }
    // ---- stage globals -> xs[:, 256:320)
    #pragma unroll
    for (int it = 0; it < 2; ++it) {
        int i = tid + it * 256;             // 0..511
        int r = i >> 4, k4 = i & 15;
        int b = batch[row0 + r];
        float4 v = *reinterpret_cast<const float4*>(
            glob + (size_t)b * GLOB_F + k4 * 4);
        cvt_store4(&xs[r * XSTR + NODE_F + EDGE_F + k4 * 4], v.x, v.y, v.z, v.w);
    }
    // ---- gather-mean edges -> xs[:, 128:256). Wave wv owns rows wv*8..wv*8+7.
    {
        int half = lane >> 5;     // even/odd edges
        int fl   = lane & 31;     // float4 slot
        for (int rr = 0; rr < 8; ++rr) {
            int r = wv * 8 + rr;
            int n = row0 + r;
            int beg = offs[n], end = offs[n + 1];
            float ax = 0.f, ay = 0.f, az = 0.f, aw = 0.f;
            for (int j = beg + half; j < end; j += 2) {
                int e = eid[j];
                float4 v = *reinterpret_cast<const float4*>(
                    edge_feats + (size_t)e * EDGE_F + fl * 4);
                ax += v.x; ay += v.y; az += v.z; aw += v.w;
            }
            ax += __shfl_xor(ax, 32);
            ay += __shfl_xor(ay, 32);
            az += __shfl_xor(az, 32);
            aw += __shfl_xor(aw, 32);
            if (half == 0) {
                float invc = 1.0f / fmaxf((float)(end - beg), 1.0f);
                cvt_store4(&xs[r * XSTR + NODE_F + fl * 4],
                           ax * invc, ay * invc, az * invc, aw * invc);
            }
        }
    }

    f32x4 acc00 = {0.f, 0.f, 0.f, 0.f};
    f32x4 acc10 = {0.f, 0.f, 0.f, 0.f};
    f32x4 acc01 = {0.f, 0.f, 0.f, 0.f};
    f32x4 acc11 = {0.f, 0.f, 0.f, 0.f};

    const int lr = lane & 15;    // row/col within MFMA tile
    const int kb = lane >> 4;    // k-block of 8

    for (int kt = 0; kt < IN_DIM / 32; ++kt) {     // 10 k-steps
        __syncthreads();                           // wb reuse guard (also covers xs on kt=0)
        // stage W k-tile: wb[o][kk] = wbf[o][kt*32+kk]
        #pragma unroll
        for (int it = 0; it < 4; ++it) {
            int i = tid + it * 256;                // 0..1023
            int o = i >> 3, k4 = i & 7;
            bf16x4 v = *reinterpret_cast<const bf16x4*>(
                wbf + (size_t)o * IN_DIM + kt * 32 + k4 * 4);
            *reinterpret_cast<bf16x4*>(&wb[o * WSTR + k4 * 4]) = v;
        }
        __syncthreads();

        bf16x8 a0 = *reinterpret_cast<const bf16x8*>(&xs[lr * XSTR + kt * 32 + kb * 8]);
        bf16x8 a1 = *reinterpret_cast<const bf16x8*>(&xs[(16 + lr) * XSTR + kt * 32 + kb * 8]);
        bf16x8 b0 = *reinterpret_cast<const bf16x8*>(&wb[(wv * 32 + lr) * WSTR + kb * 8]);
        bf16x8 b1 = *reinterpret_cast<const bf16x8*>(&wb[(wv * 32 + 16 + lr) * WSTR + kb * 8]);

        acc00 = __builtin_amdgcn_mfma_f32_16x16x32_bf16(a0, b0, acc00, 0, 0, 0);
        acc10 = __builtin_amdgcn_mfma_f32_16x16x32_bf16(a1, b0, acc10, 0, 0, 0);
        acc01 = __builtin_amdgcn_mfma_f32_16x16x32_bf16(a0, b1, acc01, 0, 0, 0);
        acc11 = __builtin_amdgcn_mfma_f32_16x16x32_bf16(a1, b1, acc11, 0, 0, 0);
    }

    // ---- epilogue: shifted softplus, C/D layout col=lane&15, row=(lane>>4)*4+q
    const float LN2 = 0.69314718055994530942f;
#define EMIT(ACC, RT, CT)                                                      \
    do {                                                                       \
        int col = (wv * 2 + (CT)) * 16 + lr;                                   \
        _Pragma("unroll")                                                      \
        for (int q = 0; q < 4; ++q) {                                          \
            int row = row0 + (RT) * 16 + kb * 4 + q;                           \
            float h = ACC[q];                                                  \
            float sp = fmaxf(h, 0.f) + log1pf(__expf(-fabsf(h)));              \
            out[(size_t)row * HIDDEN + col] = sp - LN2;                        \
        }                                                                      \
    } while (0)
    EMIT(acc00, 0, 0);
    EMIT(acc10, 1, 0);
    EMIT(acc01, 0, 1);
    EMIT(acc11, 1, 1);
#undef EMIT
}

// ---------------------------------------------------------------------------
extern "C" void kernel_launch(void* const* d_in, const int* in_sizes, int n_in,
                              void* d_out, int out_size, void* d_ws, size_t ws_size,
                              hipStream_t stream) {
    const float* node_feats = (const float*)d_in[0];   // [100000,128]
    const float* edge_feats = (const float*)d_in[1];   // [1600000,128]
    const float* glob       = (const float*)d_in[2];   // [256,64]
    const float* W          = (const float*)d_in[3];   // [128,320]
    const int*   edge_index = (const int*)d_in[4];     // [2,1600000]
    const int*   batch      = (const int*)d_in[5];     // [100000]
    float* out = (float*)d_out;                        // [100000,128]

    const int* dst = edge_index + N_EDGES;             // row 1 = destinations

    // workspace layout
    __bf16* wbf = (__bf16*)d_ws;                       // 40960 bf16 = 81920 B
    int* ws_i   = (int*)((char*)d_ws + 81920);
    int* counts  = ws_i;                               // 100000
    int* partial = ws_i + 100000;                      // 64
    int* pscan   = ws_i + 100064;                      // 64
    int* offs    = ws_i + 100128;                      // 100001
    int* cursor  = ws_i + 200132;                      // 100000
    int* eid     = ws_i + 300132;                      // 1600000  (ends ~7.7 MB)

    hipMemsetAsync(counts, 0, (size_t)N_NODES * sizeof(int), stream);

    wbf_kernel<<<160, 256, 0, stream>>>(W, wbf);
    hist_kernel<<<N_EDGES / 256, 256, 0, stream>>>(dst, counts);
    scan1_kernel<<<NSCAN, 256, 0, stream>>>(counts, partial);
    scan2_kernel<<<1, 64, 0, stream>>>(partial, pscan);
    scan3_kernel<<<NSCAN, 256, 0, stream>>>(counts, pscan, offs, cursor);
    fill_kernel<<<N_EDGES / 256, 256, 0, stream>>>(dst, cursor, eid);

    fused_kernel<<<N_NODES / ROWS, 256, 0, stream>>>(
        node_feats, edge_feats, glob, batch, wbf, offs, eid, out);
}

// Round 3
// 445.016 us; speedup vs baseline: 7.2939x; 1.2780x over previous
//
#include <hip/hip_runtime.h>
#include <math.h>

#define N_NODES   100000
#define N_EDGES   1600000
#define NODE_F    128
#define EDGE_F    128
#define GLOB_F    64
#define N_GRAPHS  256
#define HIDDEN    128
#define IN_DIM    320   // 128 + 128 + 64

#define SCAN_CHUNK 2048
#define NSCAN ((N_NODES + SCAN_CHUNK - 1) / SCAN_CHUNK)   // 49

typedef __bf16 bf16x8 __attribute__((ext_vector_type(8)));
typedef __bf16 bf16x4 __attribute__((ext_vector_type(4)));
typedef float  f32x4  __attribute__((ext_vector_type(4)));

__device__ __forceinline__ void cvt_store4(__bf16* p, float x, float y, float z, float w) {
    bf16x4 b = { (__bf16)x, (__bf16)y, (__bf16)z, (__bf16)w };
    *reinterpret_cast<bf16x4*>(p) = b;
}

// ---------------------------------------------------------------------------
// W (f32 [128,320]) -> bf16, once.
// ---------------------------------------------------------------------------
__global__ __launch_bounds__(256) void wbf_kernel(const float* __restrict__ W,
                                                  __bf16* __restrict__ wbf) {
    int i = blockIdx.x * 256 + threadIdx.x;   // 160 blocks x 256 = 40960 exact
    wbf[i] = (__bf16)W[i];
}

// ---------------------------------------------------------------------------
// CSR build: histogram -> scan -> fill
// ---------------------------------------------------------------------------
__global__ __launch_bounds__(256) void hist_kernel(const int* __restrict__ dst,
                                                   int* __restrict__ counts) {
    int i = blockIdx.x * 256 + threadIdx.x;   // 6250 x 256 = 1.6M exact
    if (i < N_EDGES) atomicAdd(&counts[dst[i]], 1);
}

__global__ __launch_bounds__(256) void scan1_kernel(const int* __restrict__ counts,
                                                    int* __restrict__ partial) {
    __shared__ int red[256];
    int tid = threadIdx.x;
    int base = blockIdx.x * SCAN_CHUNK + tid * 8;
    int s = 0;
    #pragma unroll
    for (int j = 0; j < 8; ++j) {
        int idx = base + j;
        if (idx < N_NODES) s += counts[idx];
    }
    red[tid] = s;
    __syncthreads();
    for (int off = 128; off > 0; off >>= 1) {
        if (tid < off) red[tid] += red[tid + off];
        __syncthreads();
    }
    if (tid == 0) partial[blockIdx.x] = red[0];
}

__global__ __launch_bounds__(64) void scan2_kernel(const int* __restrict__ partial,
                                                   int* __restrict__ pscan) {
    if (threadIdx.x == 0) {
        int run = 0;
        for (int b = 0; b < NSCAN; ++b) { pscan[b] = run; run += partial[b]; }
    }
}

__global__ __launch_bounds__(256) void scan3_kernel(const int* __restrict__ counts,
                                                    const int* __restrict__ pscan,
                                                    int* __restrict__ offs,
                                                    int* __restrict__ cursor) {
    __shared__ int ts[256];
    int tid = threadIdx.x;
    int base = blockIdx.x * SCAN_CHUNK + tid * 8;
    int c[8];
    int tot = 0;
    #pragma unroll
    for (int j = 0; j < 8; ++j) {
        int idx = base + j;
        c[j] = (idx < N_NODES) ? counts[idx] : 0;
        tot += c[j];
    }
    ts[tid] = tot;
    __syncthreads();
    for (int off = 1; off < 256; off <<= 1) {
        int v = 0;
        if (tid >= off) v = ts[tid - off];
        __syncthreads();
        if (tid >= off) ts[tid] += v;
        __syncthreads();
    }
    int run = pscan[blockIdx.x] + ts[tid] - tot;   // exclusive prefix
    #pragma unroll
    for (int j = 0; j < 8; ++j) {
        int idx = base + j;
        if (idx < N_NODES) { offs[idx] = run; cursor[idx] = run; run += c[j]; }
    }
    if (blockIdx.x == 0 && tid == 0) offs[N_NODES] = N_EDGES;
}

__global__ __launch_bounds__(256) void fill_kernel(const int* __restrict__ dst,
                                                   int* __restrict__ cursor,
                                                   int* __restrict__ eid) {
    int i = blockIdx.x * 256 + threadIdx.x;
    if (i < N_EDGES) {
        int d = dst[i];
        int pos = atomicAdd(&cursor[d], 1);
        eid[pos] = i;
    }
}

// ---------------------------------------------------------------------------
// Fused: CSR gather-mean + concat (into LDS as bf16) + MFMA GEMM + softplus.
// Block = 256 threads (4 waves), 32 rows x 128 cols of output.
// Gather: each wave = 4 x 16-lane groups; group handles one row at a time
// (2 passes). eids preloaded 16-at-a-time into regs, broadcast via shfl ->
// edge-row loads have no memory-dependent addressing (full ILP).
// GEMM: A from LDS, B (W) read directly from L2-resident global bf16 copy.
// k-loop is barrier-free.
// ---------------------------------------------------------------------------
#define ROWS 32
#define XSTR (IN_DIM + 8)     // 328 bf16 -> 656 B row stride (16B-aligned)

__global__ __launch_bounds__(256) void fused_kernel(
    const float* __restrict__ node_feats,   // [N_NODES,128]
    const float* __restrict__ edge_feats,   // [N_EDGES,128]
    const float* __restrict__ glob,         // [256,64]
    const int*   __restrict__ batch,        // [N_NODES]
    const __bf16* __restrict__ wbf,         // [128,320] bf16
    const int*   __restrict__ offs,         // [N_NODES+1]
    const int*   __restrict__ eid,          // [N_EDGES]
    float* __restrict__ out)                // [N_NODES,128]
{
    __shared__ __bf16 xs[ROWS * XSTR];      // 20992 B (only LDS use)

    const int tid  = threadIdx.x;
    const int row0 = blockIdx.x * ROWS;
    const int wv   = tid >> 6;
    const int lane = tid & 63;
    const int gl   = lane & 15;             // lane within 16-group
    const int grp  = lane >> 4;             // group 0..3

    // ---- stage node features -> xs[:, 0:128)
    #pragma unroll
    for (int it = 0; it < 4; ++it) {
        int i = tid + it * 256;             // 0..1023
        int r = i >> 5, k4 = i & 31;
        float4 v = *reinterpret_cast<const float4*>(
            node_feats + (size_t)(row0 + r) * NODE_F + k4 * 4);
        cvt_store4(&xs[r * XSTR + k4 * 4], v.x, v.y, v.z, v.w);
    }
    // ---- stage globals -> xs[:, 256:320)
    #pragma unroll
    for (int it = 0; it < 2; ++it) {
        int i = tid + it * 256;             // 0..511
        int r = i >> 4, k4 = i & 15;
        int b = batch[row0 + r];
        float4 v = *reinterpret_cast<const float4*>(
            glob + (size_t)b * GLOB_F + k4 * 4);
        cvt_store4(&xs[r * XSTR + NODE_F + EDGE_F + k4 * 4], v.x, v.y, v.z, v.w);
    }

    // ---- gather-mean edges -> xs[:, 128:256)
    // wave wv owns rows wv*8..wv*8+7; group grp does rows wv*8+grp, wv*8+4+grp.
    #pragma unroll
    for (int rr = 0; rr < 2; ++rr) {
        int r = wv * 8 + rr * 4 + grp;
        int n = row0 + r;
        int beg = offs[n];
        int E   = offs[n + 1] - beg;
        float a0 = 0.f, a1 = 0.f, a2 = 0.f, a3 = 0.f;
        float a4 = 0.f, a5 = 0.f, a6 = 0.f, a7 = 0.f;
        for (int c0 = 0; c0 < E; c0 += 16) {
            int ev = 0;
            if (c0 + gl < E) ev = eid[beg + c0 + gl];
            #pragma unroll
            for (int i = 0; i < 16; ++i) {
                int e = __shfl(ev, (lane & 48) + i);
                if (c0 + i < E) {
                    const float4* p = reinterpret_cast<const float4*>(
                        edge_feats + (size_t)e * EDGE_F + gl * 8);
                    float4 v0 = p[0];
                    float4 v1 = p[1];
                    a0 += v0.x; a1 += v0.y; a2 += v0.z; a3 += v0.w;
                    a4 += v1.x; a5 += v1.y; a6 += v1.z; a7 += v1.w;
                }
            }
        }
        float invc = 1.0f / fmaxf((float)E, 1.0f);
        bf16x8 b;
        b[0] = (__bf16)(a0 * invc); b[1] = (__bf16)(a1 * invc);
        b[2] = (__bf16)(a2 * invc); b[3] = (__bf16)(a3 * invc);
        b[4] = (__bf16)(a4 * invc); b[5] = (__bf16)(a5 * invc);
        b[6] = (__bf16)(a6 * invc); b[7] = (__bf16)(a7 * invc);
        *reinterpret_cast<bf16x8*>(&xs[r * XSTR + NODE_F + gl * 8]) = b;
    }

    __syncthreads();   // xs complete; k-loop below is barrier-free

    f32x4 acc00 = {0.f, 0.f, 0.f, 0.f};
    f32x4 acc10 = {0.f, 0.f, 0.f, 0.f};
    f32x4 acc01 = {0.f, 0.f, 0.f, 0.f};
    f32x4 acc11 = {0.f, 0.f, 0.f, 0.f};

    const int lr = lane & 15;    // row/col within MFMA tile
    const int kb = lane >> 4;    // k-block of 8

    const __bf16* wrow0 = wbf + (size_t)(wv * 32 + lr) * IN_DIM + kb * 8;
    const __bf16* wrow1 = wrow0 + 16 * IN_DIM;

    #pragma unroll 2
    for (int kt = 0; kt < IN_DIM / 32; ++kt) {     // 10 k-steps
        bf16x8 a0 = *reinterpret_cast<const bf16x8*>(&xs[lr * XSTR + kt * 32 + kb * 8]);
        bf16x8 a1 = *reinterpret_cast<const bf16x8*>(&xs[(16 + lr) * XSTR + kt * 32 + kb * 8]);
        bf16x8 b0 = *reinterpret_cast<const bf16x8*>(wrow0 + kt * 32);
        bf16x8 b1 = *reinterpret_cast<const bf16x8*>(wrow1 + kt * 32);

        acc00 = __builtin_amdgcn_mfma_f32_16x16x32_bf16(a0, b0, acc00, 0, 0, 0);
        acc10 = __builtin_amdgcn_mfma_f32_16x16x32_bf16(a1, b0, acc10, 0, 0, 0);
        acc01 = __builtin_amdgcn_mfma_f32_16x16x32_bf16(a0, b1, acc01, 0, 0, 0);
        acc11 = __builtin_amdgcn_mfma_f32_16x16x32_bf16(a1, b1, acc11, 0, 0, 0);
    }

    // ---- epilogue: shifted softplus, C/D layout col=lane&15, row=(lane>>4)*4+q
    const float LN2 = 0.69314718055994530942f;
#define EMIT(ACC, RT, CT)                                                      \
    do {                                                                       \
        int col = (wv * 2 + (CT)) * 16 + lr;                                   \
        _Pragma("unroll")                                                      \
        for (int q = 0; q < 4; ++q) {                                          \
            int row = row0 + (RT) * 16 + kb * 4 + q;                           \
            float h = ACC[q];                                                  \
            float sp = fmaxf(h, 0.f) + log1pf(__expf(-fabsf(h)));              \
            out[(size_t)row * HIDDEN + col] = sp - LN2;                        \
        }                                                                      \
    } while (0)
    EMIT(acc00, 0, 0);
    EMIT(acc10, 1, 0);
    EMIT(acc01, 0, 1);
    EMIT(acc11, 1, 1);
#undef EMIT
}

// ---------------------------------------------------------------------------
extern "C" void kernel_launch(void* const* d_in, const int* in_sizes, int n_in,
                              void* d_out, int out_size, void* d_ws, size_t ws_size,
                              hipStream_t stream) {
    const float* node_feats = (const float*)d_in[0];   // [100000,128]
    const float* edge_feats = (const float*)d_in[1];   // [1600000,128]
    const float* glob       = (const float*)d_in[2];   // [256,64]
    const float* W          = (const float*)d_in[3];   // [128,320]
    const int*   edge_index = (const int*)d_in[4];     // [2,1600000]
    const int*   batch      = (const int*)d_in[5];     // [100000]
    float* out = (float*)d_out;                        // [100000,128]

    const int* dst = edge_index + N_EDGES;             // row 1 = destinations

    // workspace layout
    __bf16* wbf = (__bf16*)d_ws;                       // 40960 bf16 = 81920 B
    int* ws_i   = (int*)((char*)d_ws + 81920);
    int* counts  = ws_i;                               // 100000
    int* partial = ws_i + 100000;                      // 64
    int* pscan   = ws_i + 100064;                      // 64
    int* offs    = ws_i + 100128;                      // 100001
    int* cursor  = ws_i + 200132;                      // 100000
    int* eid     = ws_i + 300132;                      // 1600000  (ends ~7.7 MB)

    hipMemsetAsync(counts, 0, (size_t)N_NODES * sizeof(int), stream);

    wbf_kernel<<<160, 256, 0, stream>>>(W, wbf);
    hist_kernel<<<N_EDGES / 256, 256, 0, stream>>>(dst, counts);
    scan1_kernel<<<NSCAN, 256, 0, stream>>>(counts, partial);
    scan2_kernel<<<1, 64, 0, stream>>>(partial, pscan);
    scan3_kernel<<<NSCAN, 256, 0, stream>>>(counts, pscan, offs, cursor);
    fill_kernel<<<N_EDGES / 256, 256, 0, stream>>>(dst, cursor, eid);

    fused_kernel<<<N_NODES / ROWS, 256, 0, stream>>>(
        node_feats, edge_feats, glob, batch, wbf, offs, eid, out);
}